// Round 5
// baseline (91.582 us; speedup 1.0000x reference)
//
#include <hip/hip_runtime.h>

#define B_    8
#define OXD   30
#define OYD   30
#define OZD   14
#define NLOC  (OXD*OYD*OZD)      // 12600
#define F_    16
#define T_    216                // 3*3*3*8
#define WPL   (T_*F_)            // 3456 weights per location
#define WPL4  (WPL/4)            // 864 float4
#define NQ    5                  // locations per block
#define NBLK  (NLOC/NQ)          // 2520

__global__ __launch_bounds__(128)
void lc3d_kernel(const float* __restrict__ in, const float* __restrict__ wgt,
                 const float* __restrict__ bias, float* __restrict__ out) {
    __shared__ float patch[B_ * T_];   // 6.9 KB, reused across the 5 locations
    __shared__ float red[2][2 * 128];  // double-buffered cross-wave partials, 2 KB
    float4* patch4 = reinterpret_cast<float4*>(patch);
    const float4* in4  = reinterpret_cast<const float4*>(in);
    const float4* wgt4 = reinterpret_cast<const float4*>(wgt);

    const int tid  = threadIdx.x;
    const int fq   = tid & 3;          // f quadrant
    const int tg   = tid >> 2;         // 0..31 t-group
    const int loc0 = blockIdx.x * NQ;

    // ---- per-thread patch-load bases, location-independent part.
    // idx = tid + 128r covers 432 float4 (r=3 only for tid<48).
    // flat float4 addr = base4[r] + ((ox*32+oy)*16+oz)*2
    int base4[4];
    #pragma unroll
    for (int r = 0; r < 4; ++r) {
        int idx = tid + 128 * r;
        int seg = idx / 6;             // b*9 + ij
        int off = idx - seg * 6;
        int b   = seg / 9;
        int ij  = seg - b * 9;
        int i   = ij / 3;
        int j   = ij - i * 3;
        base4[r] = (((b * 32 + i) * 32 + j) * 16) * 2 + off;
    }

    // ---- prologue: issue loc0's weight + patch loads
    float4 w[7], p[4];
    {
        const int loc = loc0;
        const int ox  = loc / (OYD * OZD);
        const int rem = loc - ox * (OYD * OZD);
        const int oy  = rem / OZD;
        const int oz  = rem - oy * OZD;
        const int lo4 = ((ox * 32 + oy) * 16 + oz) * 2;
        const float4* wl = wgt4 + (size_t)loc * WPL4 + tid;
        #pragma unroll
        for (int it = 0; it < 6; ++it) w[it] = wl[it * 128];
        w[6] = make_float4(0.f, 0.f, 0.f, 0.f);
        if (tid < 96) w[6] = wl[6 * 128];          // tg<24
        #pragma unroll
        for (int r = 0; r < 3; ++r) p[r] = in4[base4[r] + lo4];
        if (tid < 48) p[3] = in4[base4[3] + lo4];
    }

    #pragma unroll
    for (int q = 0; q < NQ; ++q) {
        const int loc = loc0 + q;

        // ---- commit prefetched patch regs to LDS
        #pragma unroll
        for (int r = 0; r < 3; ++r) patch4[tid + 128 * r] = p[r];
        if (tid < 48) patch4[tid + 384] = p[3];
        __syncthreads();

        // ---- issue NEXT location's loads; they fly during this compute
        float4 w2[7], p2[4];
        if (q + 1 < NQ) {
            const int nl  = loc + 1;
            const int ox  = nl / (OYD * OZD);
            const int rem = nl - ox * (OYD * OZD);
            const int oy  = rem / OZD;
            const int oz  = rem - oy * OZD;
            const int lo4 = ((ox * 32 + oy) * 16 + oz) * 2;
            const float4* wl = wgt4 + (size_t)nl * WPL4 + tid;
            #pragma unroll
            for (int it = 0; it < 6; ++it) w2[it] = wl[it * 128];
            w2[6] = make_float4(0.f, 0.f, 0.f, 0.f);
            if (tid < 96) w2[6] = wl[6 * 128];
            #pragma unroll
            for (int r = 0; r < 3; ++r) p2[r] = in4[base4[r] + lo4];
            if (tid < 48) p2[3] = in4[base4[3] + lo4];
        }

        const float bi = bias[(size_t)loc * F_ + (tid & 15)];

        // ---- compute (identical to R3's verified loop)
        float a[32];
        #pragma unroll
        for (int e = 0; e < 32; ++e) a[e] = 0.f;

        #pragma unroll
        for (int it = 0; it < 7; ++it) {
            const int t  = tg + 32 * it;
            const int tc = (t < T_) ? t : 0;   // clamp; w[6]=0 there
            const float4 ww = w[it];
            #pragma unroll
            for (int b = 0; b < B_; ++b) {
                const float ps = patch[b * T_ + tc];
                a[b * 4 + 0] += ps * ww.x;
                a[b * 4 + 1] += ps * ww.y;
                a[b * 4 + 2] += ps * ww.z;
                a[b * 4 + 3] += ps * ww.w;
            }
        }

        // ---- in-wave butterfly: 16 t-groups, element-folding (30 shuffles)
#define RSTEP(m, k)                                         \
        {                                                   \
            const bool hi = (tid & (m)) != 0;               \
            _Pragma("unroll")                               \
            for (int e = 0; e < (k); ++e) {                 \
                float v = hi ? a[e] : a[e + (k)];           \
                float r = __shfl_xor(v, (m), 64);           \
                a[e] = (hi ? a[e + (k)] : a[e]) + r;        \
            }                                               \
        }
        RSTEP(4, 16)
        RSTEP(8, 8)
        RSTEP(16, 4)
        RSTEP(32, 2)
#undef RSTEP

        const int eg = ((tid & 4) << 2) | (tid & 8) | ((tid & 16) >> 2) | ((tid & 32) >> 4);
        const int wv = tid >> 6;
        red[q & 1][wv * 128 + (eg + 0) * 4 + fq] = a[0];
        red[q & 1][wv * 128 + (eg + 1) * 4 + fq] = a[1];
        __syncthreads();   // also guarantees all patch reads done before next q

        {
            const int b  = tid >> 4;
            const int f  = tid & 15;
            const int e2 = ((b * 4 + (f & 3)) * 4) + (f >> 2);
            const float s = bi + red[q & 1][e2] + red[q & 1][128 + e2];
            out[((size_t)b * NLOC + loc) * F_ + f] = s;
        }

        // ---- rotate prefetch into current (free: loop is fully unrolled)
        if (q + 1 < NQ) {
            #pragma unroll
            for (int it = 0; it < 7; ++it) w[it] = w2[it];
            #pragma unroll
            for (int r = 0; r < 4; ++r) p[r] = p2[r];
        }
    }
}

extern "C" void kernel_launch(void* const* d_in, const int* in_sizes, int n_in,
                              void* d_out, int out_size, void* d_ws, size_t ws_size,
                              hipStream_t stream) {
    const float* in   = (const float*)d_in[0];
    const float* wgt  = (const float*)d_in[1];
    const float* bias = (const float*)d_in[2];
    float* out = (float*)d_out;
    lc3d_kernel<<<NBLK, 128, 0, stream>>>(in, wgt, bias, out);
}